// Round 1
// baseline (329.336 us; speedup 1.0000x reference)
//
#include <hip/hip_runtime.h>

// Adaptive avg pool 2D: in (32,50,50,768) f32 NHWC -> out (32,7,7,768).
// For in=50, out=7: start_i = (i*50)/7, window size is 8 for every i.
// Output = mean over the 8x8 (h,w) window, per channel.

#define N_  32
#define HIN 50
#define WIN 50
#define C_  768
#define HOUT 7
#define WOUT 7
#define CG (C_ / 4)           // 192 float4 groups per pixel
#define TOTAL (N_ * HOUT * WOUT * CG)

__global__ __launch_bounds__(256) void adaptive_pool_kernel(
    const float4* __restrict__ in, float4* __restrict__ out) {
    int idx = blockIdx.x * blockDim.x + threadIdx.x;
    if (idx >= TOTAL) return;

    int cg = idx % CG;
    int t  = idx / CG;
    int wo = t % WOUT; t /= WOUT;
    int ho = t % HOUT;
    int n  = t / HOUT;

    int hs = (ho * HIN) / HOUT;   // 0,7,14,21,28,35,42
    int ws = (wo * WIN) / WOUT;

    const float4* base = in + ((size_t)((n * HIN + hs) * WIN + ws)) * CG + cg;

    float4 acc = make_float4(0.f, 0.f, 0.f, 0.f);
    for (int dh = 0; dh < 8; ++dh) {
        const float4* rp = base + (size_t)dh * (WIN * CG);
        #pragma unroll
        for (int dw = 0; dw < 8; ++dw) {
            float4 v = rp[(size_t)dw * CG];
            acc.x += v.x; acc.y += v.y; acc.z += v.z; acc.w += v.w;
        }
    }
    const float s = 1.0f / 64.0f;
    acc.x *= s; acc.y *= s; acc.z *= s; acc.w *= s;
    out[idx] = acc;
}

extern "C" void kernel_launch(void* const* d_in, const int* in_sizes, int n_in,
                              void* d_out, int out_size, void* d_ws, size_t ws_size,
                              hipStream_t stream) {
    const float4* in  = (const float4*)d_in[0];
    float4*       out = (float4*)d_out;
    int threads = 256;
    int blocks = (TOTAL + threads - 1) / threads;
    adaptive_pool_kernel<<<blocks, threads, 0, stream>>>(in, out);
}